// Round 5
// baseline (1029.817 us; speedup 1.0000x reference)
//
#include <hip/hip_runtime.h>
#include <hip/hip_bf16.h>

// ActLayer: out[b,o] = sum_{i,f} norm(sin(w_f x[b,i] + p_f)) * beta[f,o] * lamb[i,o] + bias[o]
//
// Round-7: round-3's verified wave structure (register-sin A-path, per-f barrier
// cadence, brP prefetch) with an occupancy fix that adds NO work and NO atomics:
//   1. L_sh eliminated: each wave needs the whole Lambda tile anyway (no
//      cross-wave reuse LDS adds over L2; lamb is 1MB, L2-resident). Lambda
//      fragments are loaded straight from global and packed, once per i-tile.
//   2. Blocks shrunk to TB=128 (2 waves), BM=32, grid 1024 (256 m x 4 n).
//      Per-wave work identical (16 rows x 128 cols strip). LDS ~18KB ->
//      8 blocks/CU = 16 waves/CU (4/SIMD), 2x the TLP of round-3.
// Main loop touches only read-only LDS (brP): no new race surface.
//
// B=8192, I=512, F=64, O=512. i-chunk 64 (one f per K-step), mfma 16x16x32 bf16.

#define TB 128

typedef __attribute__((ext_vector_type(8))) short short8;
typedef __attribute__((ext_vector_type(4))) float floatx4;
typedef __attribute__((ext_vector_type(4))) unsigned int uintx4;
typedef __attribute__((ext_vector_type(4))) unsigned short ushort4t;

__device__ __forceinline__ unsigned pk_bf16(float a, float b) {
    __hip_bfloat162 h = __float22bfloat162_rn(make_float2(a, b));
    union { __hip_bfloat162 h2; unsigned u; } cv; cv.h2 = h; return cv.u;
}
__device__ __forceinline__ unsigned short f_to_bf16u(float v) {
    union { __hip_bfloat16 h; unsigned short u; } cv;
    cv.h = __float2bfloat16(v);
    return cv.u;
}
__device__ __forceinline__ float bf16u_to_f(unsigned short v) {
    union { unsigned u; float f; } cv; cv.u = ((unsigned)v) << 16; return cv.f;
}

// 8 bf16 sin values: sin(2*pi*(x*wfr + pfr)) for 8 register-resident x values.
__device__ __forceinline__ short8 sin_frag8(const float xv[8], float wfr, float pfr) {
    float s[8];
    #pragma unroll
    for (int j = 0; j < 8; ++j) {
        float arg = __builtin_amdgcn_fractf(fmaf(xv[j], wfr, pfr));
        s[j] = __builtin_amdgcn_sinf(arg);
    }
    union { uintx4 u; short8 h; } cv;
    cv.u.x = pk_bf16(s[0], s[1]); cv.u.y = pk_bf16(s[2], s[3]);
    cv.u.z = pk_bf16(s[4], s[5]); cv.u.w = pk_bf16(s[6], s[7]);
    return cv.h;
}

__global__ __launch_bounds__(TB, 4)
void actlayer_kernel(const float* __restrict__ x,
                     const float* __restrict__ freqs,
                     const float* __restrict__ phases,
                     const float* __restrict__ beta,
                     const float* __restrict__ lamb,
                     const float* __restrict__ bias,
                     float* __restrict__ out)
{
    constexpr int I = 512, F = 64, O = 512;
    constexpr int BN = 128;
    const int t  = threadIdx.x;
    const int bx = blockIdx.x;
    const int bn = bx & 3;            // 0..3
    const int bm = bx >> 2;           // 0..255
    const int n0 = bn * BN;
    const int m0 = bm * 32;

    __shared__ __align__(16) unsigned short brP_sh[F][16][8]; // betaR bf16: [f][c=o%16][w=o/16]
    __shared__ float wrev_sh[F], prev_sh[F], r_sh[F], m_sh[F];
    __shared__ float c_sh[BN];

    // ---- prologue: per-f normalization constants ----
    if (t < F) {
        float wq = freqs[t];
        float ph = phases[t];
        float e1 = expf(-0.5f * wq * wq);
        float mean = e1 * sinf(ph);
        float e2 = expf(-2.0f * wq * wq);
        float var = 0.5f - 0.5f * e2 * cosf(2.0f * ph) - mean * mean;
        float r = 1.0f / sqrtf(1e-3f + var);
        wrev_sh[t] = wq * 0.15915494309189535f;   // /2pi -> revolutions for v_sin
        prev_sh[t] = ph * 0.15915494309189535f;
        r_sh[t] = r;
        m_sh[t] = mean;
    }
    __syncthreads();
    // brP[f][c][w] = beta[f][n0 + w*16 + c] * r_f   (bf16)
    #pragma unroll
    for (int j = 0; j < 64; ++j) {
        int e = t + TB * j;          // 0..8191
        int f = e >> 7;              // 0..63
        int rem = e & 127;
        int w = rem >> 4;            // 0..7
        int c = rem & 15;
        float bv = beta[f * O + n0 + w * 16 + c] * r_sh[f];
        brP_sh[f][c][w] = f_to_bf16u(bv);
    }
    __syncthreads();
    // c_sh[n] = bias[n] - (sum_f betaR[f,n]*mean_f) * (sum_i lamb[i,n]); one col/thread
    {
        int c = t & 15, w = t >> 4;
        float sb = 0.f;
        #pragma unroll
        for (int f = 0; f < F; ++f) sb += bf16u_to_f(brP_sh[f][c][w]) * m_sh[f];
        float sl = 0.f;
        const float* lp = lamb + n0 + t;
        #pragma unroll 8
        for (int i = 0; i < I; ++i) sl += lp[(size_t)i * O];
        c_sh[t] = bias[n0 + t] - sb * sl;
    }
    __syncthreads();

    // ---- wave geometry: wave wid owns rows [m0+16*wid, +16), all 128 cols ----
    const int lane = t & 63;
    const int wid  = t >> 6;          // 0..1
    const int l15  = lane & 15;
    const int quad = lane >> 4;
    const int row  = m0 + wid * 16 + l15;

    floatx4 oacc[8];
    #pragma unroll
    for (int nt = 0; nt < 8; ++nt) oacc[nt] = (floatx4){0.f, 0.f, 0.f, 0.f};
    const floatx4 zero4 = (floatx4){0.f, 0.f, 0.f, 0.f};

    #pragma unroll 1
    for (int it = 0; it < 8; ++it) {
        const int i0 = it * 64;
        // x -> regs: exactly the 16 values this lane's A-frags need.
        float xr0[8], xr1[8];
        {
            const float* xp = x + (size_t)row * I + i0 + quad * 8;
            float4 a0 = *(const float4*)(xp);
            float4 a1 = *(const float4*)(xp + 4);
            float4 b0 = *(const float4*)(xp + 32);
            float4 b1 = *(const float4*)(xp + 36);
            xr0[0]=a0.x; xr0[1]=a0.y; xr0[2]=a0.z; xr0[3]=a0.w;
            xr0[4]=a1.x; xr0[5]=a1.y; xr0[6]=a1.z; xr0[7]=a1.w;
            xr1[0]=b0.x; xr1[1]=b0.y; xr1[2]=b0.z; xr1[3]=b0.w;
            xr1[4]=b1.x; xr1[5]=b1.y; xr1[6]=b1.z; xr1[7]=b1.w;
        }
        // lambda fragments straight from global (L2-resident), packed to bf16.
        // lf[kk][nt][j] = bf16(lamb[i0 + kk*32 + quad*8 + j][n0 + nt*16 + l15])
        short8 lf[2][8];
        #pragma unroll
        for (int kk = 0; kk < 2; ++kk) {
            #pragma unroll
            for (int nt = 0; nt < 8; ++nt) {
                const float* lp = lamb + (size_t)(i0 + kk * 32 + quad * 8) * O
                                + n0 + nt * 16 + l15;
                float v[8];
                #pragma unroll
                for (int j = 0; j < 8; ++j) v[j] = lp[(size_t)j * O];
                union { uintx4 u; short8 h; } cv;
                cv.u.x = pk_bf16(v[0], v[1]); cv.u.y = pk_bf16(v[2], v[3]);
                cv.u.z = pk_bf16(v[4], v[5]); cv.u.w = pk_bf16(v[6], v[7]);
                lf[kk][nt] = cv.h;
            }
        }
        // A fragments for f=0 (registers)
        short8 af0 = sin_frag8(xr0, wrev_sh[0], prev_sh[0]);
        short8 af1 = sin_frag8(xr1, wrev_sh[0], prev_sh[0]);
        // betaR prefetch for f=0
        ushort4t bru0 = *(const ushort4t*)&brP_sh[0][l15][0];
        ushort4t bru1 = *(const ushort4t*)&brP_sh[0][l15][4];

        // ---- f-loop, verified cadence: sin(f+1)+brP(f+1) overlap MFMA(f),
        //      barrier per f (brP is read-only; barrier kept as proven cadence) ----
        #pragma unroll 2
        for (int f = 0; f < F; ++f) {
            float br[8];
            #pragma unroll
            for (int q = 0; q < 4; ++q) {
                br[q]     = bf16u_to_f(bru0[q]);
                br[4 + q] = bf16u_to_f(bru1[q]);
            }
            // overlap: prefetch betaR + sin fragments for f+1 (registers only)
            short8 nf0 = af0, nf1 = af1;
            if (f < F - 1) {
                bru0 = *(const ushort4t*)&brP_sh[f + 1][l15][0];
                bru1 = *(const ushort4t*)&brP_sh[f + 1][l15][4];
                float wfr = wrev_sh[f + 1], pfr = prev_sh[f + 1];
                nf0 = sin_frag8(xr0, wfr, pfr);
                nf1 = sin_frag8(xr1, wfr, pfr);
            }
            // S_f = A_f @ Lambda ; out += betaR (.) S_f
            #pragma unroll
            for (int nt = 0; nt < 8; ++nt) {
                floatx4 s = __builtin_amdgcn_mfma_f32_16x16x32_bf16(
                    af0, lf[0][nt], zero4, 0, 0, 0);
                s = __builtin_amdgcn_mfma_f32_16x16x32_bf16(
                    af1, lf[1][nt], s, 0, 0, 0);
                oacc[nt] += br[nt] * s;
            }
            __syncthreads();
            af0 = nf0; af1 = nf1;
        }
    }

    // ---- epilogue: add per-column constant, store fp32 ----
    #pragma unroll
    for (int nt = 0; nt < 8; ++nt) {
        int gn = n0 + nt*16 + l15;
        float cv = c_sh[nt*16 + l15];
        int gm = m0 + wid*16 + quad*4;
        #pragma unroll
        for (int rg = 0; rg < 4; ++rg) {
            out[(size_t)(gm + rg) * O + gn] = oacc[nt][rg] + cv;
        }
    }
}

extern "C" void kernel_launch(void* const* d_in, const int* in_sizes, int n_in,
                              void* d_out, int out_size, void* d_ws, size_t ws_size,
                              hipStream_t stream) {
    const float* x      = (const float*)d_in[0];
    const float* freqs  = (const float*)d_in[1];
    const float* phases = (const float*)d_in[2];
    const float* beta   = (const float*)d_in[3];
    const float* lamb   = (const float*)d_in[4];
    const float* bias   = (const float*)d_in[5];
    float* out = (float*)d_out;

    dim3 grid(1024);   // 256 m-blocks * 4 n-blocks
    dim3 block(TB);
    hipLaunchKernelGGL(actlayer_kernel, grid, block, 0, stream,
                       x, freqs, phases, beta, lamb, bias, out);
}

// Round 6
// 913.030 us; speedup vs baseline: 1.1279x; 1.1279x over previous
//
#include <hip/hip_runtime.h>
#include <hip/hip_bf16.h>

// ActLayer: out[b,o] = sum_{i,f} norm(sin(w_f x[b,i] + p_f)) * beta[f,o] * lamb[i,o] + bias[o]
//
// Round-8: split-i via WORKSPACE (round-4's kernel body verbatim, atomics
// replaced by plain coalesced stores to d_ws) + a tiny stream-ordered
// reduction kernel out = ws0 + ws1.  Round-4 proved the split mechanics
// (passed, occupancy 47%, pipe busy-times unchanged); its 925us came purely
// from 528MB of atomic RMW HBM traffic, which plain ws stores eliminate.
//   - main: grid 1024 (128m x 4n x 2 i-halves), TB=256, 4 blocks/CU,
//     16 waves/CU = 4/SIMD (2x round-3's TLP). half-0 folds bias/c into ws0.
//   - reduce: out = ws0 + ws1, float4, fully coalesced (~50MB => ~10us).
//   - fallback: if ws_size < 2*out bytes, launch the exact round-3 champion
//     single-kernel config instead.
//
// B=8192, I=512, F=64, O=512. i-chunk 64 (one f per K-step), mfma 16x16x32 bf16.

#define TB 256
#define OUTN (8192 * 512)

typedef __attribute__((ext_vector_type(8))) short short8;
typedef __attribute__((ext_vector_type(4))) float floatx4;
typedef __attribute__((ext_vector_type(4))) unsigned int uintx4;
typedef __attribute__((ext_vector_type(4))) unsigned short ushort4t;

__device__ __forceinline__ unsigned pk_bf16(float a, float b) {
    __hip_bfloat162 h = __float22bfloat162_rn(make_float2(a, b));
    union { __hip_bfloat162 h2; unsigned u; } cv; cv.h2 = h; return cv.u;
}
__device__ __forceinline__ unsigned short f_to_bf16u(float v) {
    union { __hip_bfloat16 h; unsigned short u; } cv;
    cv.h = __float2bfloat16(v);
    return cv.u;
}
__device__ __forceinline__ float bf16u_to_f(unsigned short v) {
    union { unsigned u; float f; } cv; cv.u = ((unsigned)v) << 16; return cv.f;
}

// 8 bf16 sin values: sin(2*pi*(x*wfr + pfr)) for 8 register-resident x values.
__device__ __forceinline__ short8 sin_frag8(const float xv[8], float wfr, float pfr) {
    float s[8];
    #pragma unroll
    for (int j = 0; j < 8; ++j) {
        float arg = __builtin_amdgcn_fractf(fmaf(xv[j], wfr, pfr));
        s[j] = __builtin_amdgcn_sinf(arg);
    }
    union { uintx4 u; short8 h; } cv;
    cv.u.x = pk_bf16(s[0], s[1]); cv.u.y = pk_bf16(s[2], s[3]);
    cv.u.z = pk_bf16(s[4], s[5]); cv.u.w = pk_bf16(s[6], s[7]);
    return cv.h;
}

// ---------------- main split-i kernel (round-4 body, ws stores) ----------------
__global__ __launch_bounds__(TB, 4)
void actlayer_split(const float* __restrict__ x,
                    const float* __restrict__ freqs,
                    const float* __restrict__ phases,
                    const float* __restrict__ beta,
                    const float* __restrict__ lamb,
                    const float* __restrict__ bias,
                    float* __restrict__ ws)
{
    constexpr int I = 512, F = 64, O = 512;
    constexpr int BN = 128;
    const int t  = threadIdx.x;
    const int bx = blockIdx.x;
    const int half = bx & 1;          // i-half: 0 -> i-tiles 0..3, 1 -> 4..7
    const int bn = (bx >> 1) & 3;     // 0..3
    const int bm = bx >> 3;           // 0..127
    const int n0 = bn * BN;
    const int m0 = bm * 64;

    __shared__ __align__(16) unsigned short L_sh[BN][72];     // lambda tile (bf16), per i-tile
    __shared__ __align__(16) unsigned short brP_sh[F][16][8]; // betaR bf16: [f][c=o%16][w=o/16]
    __shared__ float wrev_sh[F], prev_sh[F], r_sh[F], m_sh[F];
    __shared__ float c_sh[BN];
    __shared__ float slp_sh[2][BN];

    // ---- prologue: per-f normalization constants ----
    if (t < F) {
        float wq = freqs[t];
        float ph = phases[t];
        float e1 = expf(-0.5f * wq * wq);
        float mean = e1 * sinf(ph);
        float e2 = expf(-2.0f * wq * wq);
        float var = 0.5f - 0.5f * e2 * cosf(2.0f * ph) - mean * mean;
        float r = 1.0f / sqrtf(1e-3f + var);
        wrev_sh[t] = wq * 0.15915494309189535f;   // /2pi -> revolutions for v_sin
        prev_sh[t] = ph * 0.15915494309189535f;
        r_sh[t] = r;
        m_sh[t] = mean;
    }
    // sl[n] = sum_i lamb[i][n0+n] (full i-range) -- only half-0 blocks need it
    if (half == 0) {
        int n = t & 127, hh = t >> 7;
        float s = 0.f;
        const float* lp = lamb + (size_t)(hh * 256) * O + n0 + n;
        #pragma unroll 8
        for (int i = 0; i < 256; ++i) s += lp[(size_t)i * O];
        slp_sh[hh][n] = s;
    }
    __syncthreads();
    // brP[f][c][w] = beta[f][n0 + w*16 + c] * r_f   (bf16)
    #pragma unroll
    for (int j = 0; j < 32; ++j) {
        int e = t + TB * j;          // 0..8191
        int f = e >> 7;              // 0..63
        int rem = e & 127;
        int w = rem >> 4;            // 0..7
        int c = rem & 15;
        float bv = beta[f * O + n0 + w * 16 + c] * r_sh[f];
        brP_sh[f][c][w] = f_to_bf16u(bv);
    }
    __syncthreads();
    if (half == 0 && t < BN) {
        int c = t & 15, w = t >> 4;
        float sb = 0.f;
        #pragma unroll
        for (int f = 0; f < F; ++f) sb += bf16u_to_f(brP_sh[f][c][w]) * m_sh[f];
        c_sh[t] = bias[n0 + t] - sb * (slp_sh[0][t] + slp_sh[1][t]);
    }

    // ---- wave geometry: wave wid owns rows [m0+16*wid, +16), all 128 cols ----
    const int lane = t & 63;
    const int wid  = t >> 6;
    const int l15  = lane & 15;
    const int quad = lane >> 4;
    const int row  = m0 + wid * 16 + l15;

    floatx4 oacc[8];
    #pragma unroll
    for (int nt = 0; nt < 8; ++nt) oacc[nt] = (floatx4){0.f, 0.f, 0.f, 0.f};
    const floatx4 zero4 = (floatx4){0.f, 0.f, 0.f, 0.f};

    const int it0 = half * 4;
    #pragma unroll 1
    for (int it = it0; it < it0 + 4; ++it) {
        const int i0 = it * 64;
        // lambda tile -> LDS (bf16), once per i-tile.
        // Protected by the f=63 barrier of the previous i-tile (round-3 cadence).
        {
            int n  = t & 127;
            int kh = t >> 7;           // 0..1
            const float* lp = lamb + (size_t)(i0 + kh * 32) * O + n0 + n;
            float v[32];
            #pragma unroll
            for (int k = 0; k < 32; ++k) v[k] = lp[(size_t)k * O];
            #pragma unroll
            for (int rr = 0; rr < 4; ++rr) {
                uintx4 w4;
                w4.x = pk_bf16(v[rr*8+0], v[rr*8+1]);
                w4.y = pk_bf16(v[rr*8+2], v[rr*8+3]);
                w4.z = pk_bf16(v[rr*8+4], v[rr*8+5]);
                w4.w = pk_bf16(v[rr*8+6], v[rr*8+7]);
                *(uintx4*)&L_sh[n][kh * 32 + rr * 8] = w4;
            }
        }
        // x -> regs: exactly the 16 values this lane's A-frags need.
        float xr0[8], xr1[8];
        {
            const float* xp = x + (size_t)row * I + i0 + quad * 8;
            float4 a0 = *(const float4*)(xp);
            float4 a1 = *(const float4*)(xp + 4);
            float4 b0 = *(const float4*)(xp + 32);
            float4 b1 = *(const float4*)(xp + 36);
            xr0[0]=a0.x; xr0[1]=a0.y; xr0[2]=a0.z; xr0[3]=a0.w;
            xr0[4]=a1.x; xr0[5]=a1.y; xr0[6]=a1.z; xr0[7]=a1.w;
            xr1[0]=b0.x; xr1[1]=b0.y; xr1[2]=b0.z; xr1[3]=b0.w;
            xr1[4]=b1.x; xr1[5]=b1.y; xr1[6]=b1.z; xr1[7]=b1.w;
        }
        // A fragments for f=0 (registers)
        short8 af0 = sin_frag8(xr0, wrev_sh[0], prev_sh[0]);
        short8 af1 = sin_frag8(xr1, wrev_sh[0], prev_sh[0]);
        __syncthreads();   // L_sh ready
        // lambda fragments (f-invariant within this i-tile) -> registers
        short8 lf[2][8];
        #pragma unroll
        for (int kk = 0; kk < 2; ++kk)
            #pragma unroll
            for (int nt = 0; nt < 8; ++nt)
                lf[kk][nt] = *(const short8*)&L_sh[nt*16 + l15][kk*32 + quad*8];

        // betaR prefetch for f=0
        ushort4t bru0 = *(const ushort4t*)&brP_sh[0][l15][0];
        ushort4t bru1 = *(const ushort4t*)&brP_sh[0][l15][4];

        // ---- f-loop, verified cadence: sin(f+1)+brP(f+1) overlap MFMA(f),
        //      barrier per f (sync structure unchanged from verified kernel) ----
        #pragma unroll 2
        for (int f = 0; f < F; ++f) {
            float br[8];
            #pragma unroll
            for (int q = 0; q < 4; ++q) {
                br[q]     = bf16u_to_f(bru0[q]);
                br[4 + q] = bf16u_to_f(bru1[q]);
            }
            // overlap: prefetch betaR + sin fragments for f+1 (registers only)
            short8 nf0 = af0, nf1 = af1;
            if (f < F - 1) {
                bru0 = *(const ushort4t*)&brP_sh[f + 1][l15][0];
                bru1 = *(const ushort4t*)&brP_sh[f + 1][l15][4];
                float wfr = wrev_sh[f + 1], pfr = prev_sh[f + 1];
                nf0 = sin_frag8(xr0, wfr, pfr);
                nf1 = sin_frag8(xr1, wfr, pfr);
            }
            // S_f = A_f @ Lambda ; out += betaR (.) S_f
            #pragma unroll
            for (int nt = 0; nt < 8; ++nt) {
                floatx4 s = __builtin_amdgcn_mfma_f32_16x16x32_bf16(
                    af0, lf[0][nt], zero4, 0, 0, 0);
                s = __builtin_amdgcn_mfma_f32_16x16x32_bf16(
                    af1, lf[1][nt], s, 0, 0, 0);
                oacc[nt] += br[nt] * s;
            }
            __syncthreads();
            af0 = nf0; af1 = nf1;
        }
    }

    // ---- epilogue: plain coalesced store of partial (+c for half-0) to ws ----
    float* wsH = ws + (size_t)half * OUTN;
    #pragma unroll
    for (int nt = 0; nt < 8; ++nt) {
        int gn = n0 + nt*16 + l15;
        float cv = 0.f;
        if (half == 0) cv = c_sh[nt*16 + l15];
        int gm = m0 + wid*16 + quad*4;
        #pragma unroll
        for (int rg = 0; rg < 4; ++rg) {
            wsH[(size_t)(gm + rg) * 512 + gn] = oacc[nt][rg] + cv;
        }
    }
}

// ---------------- reduction: out = ws0 + ws1 (float4, coalesced) ----------------
__global__ __launch_bounds__(256)
void actlayer_reduce(const float* __restrict__ ws, float* __restrict__ out)
{
    const float4* a = (const float4*)ws;               // ws0
    const float4* b = (const float4*)(ws + OUTN);      // ws1
    float4* o = (float4*)out;
    int idx = blockIdx.x * 256 + threadIdx.x;          // 0..262143
    #pragma unroll
    for (int k = 0; k < 4; ++k) {
        int i = idx + k * 262144;                      // 4*262144 = 1,048,576 float4s
        float4 va = a[i], vb = b[i];
        o[i] = make_float4(va.x + vb.x, va.y + vb.y, va.z + vb.z, va.w + vb.w);
    }
}

// ---------------- fallback: exact round-3 champion (single kernel) ----------------
__global__ __launch_bounds__(TB, 2)
void actlayer_single(const float* __restrict__ x,
                     const float* __restrict__ freqs,
                     const float* __restrict__ phases,
                     const float* __restrict__ beta,
                     const float* __restrict__ lamb,
                     const float* __restrict__ bias,
                     float* __restrict__ out)
{
    constexpr int I = 512, F = 64, O = 512;
    constexpr int BN = 128;
    const int t  = threadIdx.x;
    const int bx = blockIdx.x;
    const int bn = bx & 3;
    const int bm = bx >> 2;
    const int n0 = bn * BN;
    const int m0 = bm * 64;

    __shared__ __align__(16) unsigned short L_sh[BN][72];
    __shared__ __align__(16) unsigned short brP_sh[F][16][12];
    __shared__ float wrev_sh[F], prev_sh[F], r_sh[F], m_sh[F];
    __shared__ float c_sh[BN];
    __shared__ float slp_sh[2][BN];

    if (t < F) {
        float wq = freqs[t];
        float ph = phases[t];
        float e1 = expf(-0.5f * wq * wq);
        float mean = e1 * sinf(ph);
        float e2 = expf(-2.0f * wq * wq);
        float var = 0.5f - 0.5f * e2 * cosf(2.0f * ph) - mean * mean;
        float r = 1.0f / sqrtf(1e-3f + var);
        wrev_sh[t] = wq * 0.15915494309189535f;
        prev_sh[t] = ph * 0.15915494309189535f;
        r_sh[t] = r;
        m_sh[t] = mean;
    }
    {
        int n = t & 127, half = t >> 7;
        float s = 0.f;
        const float* lp = lamb + (size_t)(half * 256) * O + n0 + n;
        #pragma unroll 8
        for (int i = 0; i < 256; ++i) s += lp[(size_t)i * O];
        slp_sh[half][n] = s;
    }
    __syncthreads();
    #pragma unroll
    for (int j = 0; j < 32; ++j) {
        int e = t + TB * j;
        int f = e >> 7;
        int rem = e & 127;
        int w = rem >> 4;
        int c = rem & 15;
        float bv = beta[f * O + n0 + w * 16 + c] * r_sh[f];
        brP_sh[f][c][w] = f_to_bf16u(bv);
    }
    __syncthreads();
    if (t < BN) {
        int c = t & 15, w = t >> 4;
        float sb = 0.f;
        #pragma unroll
        for (int f = 0; f < F; ++f) sb += bf16u_to_f(brP_sh[f][c][w]) * m_sh[f];
        c_sh[t] = bias[n0 + t] - sb * (slp_sh[0][t] + slp_sh[1][t]);
    }

    const int lane = t & 63;
    const int wid  = t >> 6;
    const int l15  = lane & 15;
    const int quad = lane >> 4;
    const int row  = m0 + wid * 16 + l15;

    floatx4 oacc[8];
    #pragma unroll
    for (int nt = 0; nt < 8; ++nt) oacc[nt] = (floatx4){0.f, 0.f, 0.f, 0.f};
    const floatx4 zero4 = (floatx4){0.f, 0.f, 0.f, 0.f};

    #pragma unroll 1
    for (int it = 0; it < 8; ++it) {
        const int i0 = it * 64;
        {
            int n  = t & 127;
            int kh = t >> 7;
            const float* lp = lamb + (size_t)(i0 + kh * 32) * O + n0 + n;
            float v[32];
            #pragma unroll
            for (int k = 0; k < 32; ++k) v[k] = lp[(size_t)k * O];
            #pragma unroll
            for (int rr = 0; rr < 4; ++rr) {
                uintx4 w4;
                w4.x = pk_bf16(v[rr*8+0], v[rr*8+1]);
                w4.y = pk_bf16(v[rr*8+2], v[rr*8+3]);
                w4.z = pk_bf16(v[rr*8+4], v[rr*8+5]);
                w4.w = pk_bf16(v[rr*8+6], v[rr*8+7]);
                *(uintx4*)&L_sh[n][kh * 32 + rr * 8] = w4;
            }
        }
        float xr0[8], xr1[8];
        {
            const float* xp = x + (size_t)row * I + i0 + quad * 8;
            float4 a0 = *(const float4*)(xp);
            float4 a1 = *(const float4*)(xp + 4);
            float4 b0 = *(const float4*)(xp + 32);
            float4 b1 = *(const float4*)(xp + 36);
            xr0[0]=a0.x; xr0[1]=a0.y; xr0[2]=a0.z; xr0[3]=a0.w;
            xr0[4]=a1.x; xr0[5]=a1.y; xr0[6]=a1.z; xr0[7]=a1.w;
            xr1[0]=b0.x; xr1[1]=b0.y; xr1[2]=b0.z; xr1[3]=b0.w;
            xr1[4]=b1.x; xr1[5]=b1.y; xr1[6]=b1.z; xr1[7]=b1.w;
        }
        short8 af0 = sin_frag8(xr0, wrev_sh[0], prev_sh[0]);
        short8 af1 = sin_frag8(xr1, wrev_sh[0], prev_sh[0]);
        __syncthreads();
        short8 lf[2][8];
        #pragma unroll
        for (int kk = 0; kk < 2; ++kk)
            #pragma unroll
            for (int nt = 0; nt < 8; ++nt)
                lf[kk][nt] = *(const short8*)&L_sh[nt*16 + l15][kk*32 + quad*8];

        #pragma unroll 2
        for (int f = 0; f < F; ++f) {
            ushort4t bru0 = *(const ushort4t*)&brP_sh[f][l15][0];
            ushort4t bru1 = *(const ushort4t*)&brP_sh[f][l15][4];
            float br[8];
            #pragma unroll
            for (int q = 0; q < 4; ++q) {
                br[q]     = bf16u_to_f(bru0[q]);
                br[4 + q] = bf16u_to_f(bru1[q]);
            }
            short8 nf0 = af0, nf1 = af1;
            if (f < F - 1) {
                float wfr = wrev_sh[f + 1], pfr = prev_sh[f + 1];
                nf0 = sin_frag8(xr0, wfr, pfr);
                nf1 = sin_frag8(xr1, wfr, pfr);
            }
            #pragma unroll
            for (int nt = 0; nt < 8; ++nt) {
                floatx4 s = __builtin_amdgcn_mfma_f32_16x16x32_bf16(
                    af0, lf[0][nt], zero4, 0, 0, 0);
                s = __builtin_amdgcn_mfma_f32_16x16x32_bf16(
                    af1, lf[1][nt], s, 0, 0, 0);
                oacc[nt] += br[nt] * s;
            }
            __syncthreads();
            af0 = nf0; af1 = nf1;
        }
    }

    #pragma unroll
    for (int nt = 0; nt < 8; ++nt) {
        int gn = n0 + nt*16 + l15;
        float cv = c_sh[nt*16 + l15];
        int gm = m0 + wid*16 + quad*4;
        #pragma unroll
        for (int rg = 0; rg < 4; ++rg) {
            out[(size_t)(gm + rg) * O + gn] = oacc[nt][rg] + cv;
        }
    }
}

extern "C" void kernel_launch(void* const* d_in, const int* in_sizes, int n_in,
                              void* d_out, int out_size, void* d_ws, size_t ws_size,
                              hipStream_t stream) {
    const float* x      = (const float*)d_in[0];
    const float* freqs  = (const float*)d_in[1];
    const float* phases = (const float*)d_in[2];
    const float* beta   = (const float*)d_in[3];
    const float* lamb   = (const float*)d_in[4];
    const float* bias   = (const float*)d_in[5];
    float* out = (float*)d_out;

    const size_t need = 2ull * OUTN * sizeof(float);   // 33.55 MB
    if (d_ws != nullptr && ws_size >= need) {
        float* ws = (float*)d_ws;
        hipLaunchKernelGGL(actlayer_split, dim3(1024), dim3(TB), 0, stream,
                           x, freqs, phases, beta, lamb, bias, ws);
        hipLaunchKernelGGL(actlayer_reduce, dim3(1024), dim3(256), 0, stream,
                           ws, out);
    } else {
        hipLaunchKernelGGL(actlayer_single, dim3(512), dim3(TB), 0, stream,
                           x, freqs, phases, beta, lamb, bias, out);
    }
}

// Round 7
// 480.746 us; speedup vs baseline: 2.1421x; 1.8992x over previous
//
#include <hip/hip_runtime.h>
#include <hip/hip_bf16.h>

// ActLayer: out[b,o] = sum_{i,f} norm(sin(w_f x[b,i] + p_f)) * beta[f,o] * lamb[i,o] + bias[o]
//
// Round-9: back to the round-3 champion (500us, verified), plus two local changes:
//   1. Range reduction for v_sin: fract (trans, 8cy) -> t - rintf(t)
//      (v_rndne + v_sub, full-rate, 4cy). Mathematically exact (integer period).
//      Cuts ~15% of VALU-pipe time (trans unit dominates the sin path).
//   2. f-loop fused 2 steps per barrier (512 -> 256 barriers, 2 independent
//      MFMA chains per window). brP/wp layouts, L_sh staging, per-pair barrier
//      cadence, epilogue: identical to the verified kernel. brP values are
//      prefetched into registers one pair ahead (proven safe in R4/R6).
//
// B=8192, I=512, F=64, O=512. BM=64, BN=128, i-chunk 64 (one f per K-step).
// 256 threads = 4 waves, wave w owns rows [m0+16w,+16) x 128 cols,
// mfma 16x16x32 bf16. Grid = 512 -> 2 blocks/CU.

#define TB 256

typedef __attribute__((ext_vector_type(8))) short short8;
typedef __attribute__((ext_vector_type(4))) float floatx4;
typedef __attribute__((ext_vector_type(4))) unsigned int uintx4;
typedef __attribute__((ext_vector_type(4))) unsigned short ushort4t;

__device__ __forceinline__ unsigned pk_bf16(float a, float b) {
    __hip_bfloat162 h = __float22bfloat162_rn(make_float2(a, b));
    union { __hip_bfloat162 h2; unsigned u; } cv; cv.h2 = h; return cv.u;
}
__device__ __forceinline__ unsigned short f_to_bf16u(float v) {
    union { __hip_bfloat16 h; unsigned short u; } cv;
    cv.h = __float2bfloat16(v);
    return cv.u;
}
__device__ __forceinline__ float bf16u_to_f(unsigned short v) {
    union { unsigned u; float f; } cv; cv.u = ((unsigned)v) << 16; return cv.f;
}

// 8 bf16 sin values: sin(2*pi*(x*wfr + pfr)) for 8 register-resident x values.
// Range reduction via rndne (full-rate) instead of fract (quarter-rate trans):
// u = t - round(t) in [-0.5, 0.5]; sin(2*pi*u) == sin(2*pi*t) exactly.
__device__ __forceinline__ short8 sin_frag8(const float xv[8], float wfr, float pfr) {
    float s[8];
    #pragma unroll
    for (int j = 0; j < 8; ++j) {
        float t = fmaf(xv[j], wfr, pfr);
        float u = t - __builtin_rintf(t);
        s[j] = __builtin_amdgcn_sinf(u);
    }
    union { uintx4 u; short8 h; } cv;
    cv.u.x = pk_bf16(s[0], s[1]); cv.u.y = pk_bf16(s[2], s[3]);
    cv.u.z = pk_bf16(s[4], s[5]); cv.u.w = pk_bf16(s[6], s[7]);
    return cv.h;
}

__global__ __launch_bounds__(TB, 2)
void actlayer_kernel(const float* __restrict__ x,
                     const float* __restrict__ freqs,
                     const float* __restrict__ phases,
                     const float* __restrict__ beta,
                     const float* __restrict__ lamb,
                     const float* __restrict__ bias,
                     float* __restrict__ out)
{
    constexpr int I = 512, F = 64, O = 512;
    constexpr int BN = 128;
    const int t  = threadIdx.x;
    const int bx = blockIdx.x;
    const int bn = bx & 3;            // 0..3
    const int bm = bx >> 2;           // 0..127
    const int n0 = bn * BN;
    const int m0 = bm * 64;

    // pad 72 shorts = 144 B rows: 16B-aligned for b128 everywhere
    __shared__ __align__(16) unsigned short L_sh[BN][72];      // lambda tile (bf16), per i-tile
    __shared__ __align__(16) unsigned short brP_sh[F][16][12]; // betaR bf16: [f][c=o%16][w=o/16]
    __shared__ float wrev_sh[F], prev_sh[F], r_sh[F], m_sh[F];
    __shared__ float c_sh[BN];
    __shared__ float slp_sh[2][BN];

    // ---- prologue: per-f normalization constants (verbatim round-3) ----
    if (t < F) {
        float wq = freqs[t];
        float ph = phases[t];
        float e1 = expf(-0.5f * wq * wq);
        float mean = e1 * sinf(ph);
        float e2 = expf(-2.0f * wq * wq);
        float var = 0.5f - 0.5f * e2 * cosf(2.0f * ph) - mean * mean;
        float r = 1.0f / sqrtf(1e-3f + var);
        wrev_sh[t] = wq * 0.15915494309189535f;   // /2pi -> revolutions for v_sin
        prev_sh[t] = ph * 0.15915494309189535f;
        r_sh[t] = r;
        m_sh[t] = mean;
    }
    // sl[n] = sum_i lamb[i][n0+n], split over 2 halves of i
    {
        int n = t & 127, half = t >> 7;
        float s = 0.f;
        const float* lp = lamb + (size_t)(half * 256) * O + n0 + n;
        #pragma unroll 8
        for (int i = 0; i < 256; ++i) s += lp[(size_t)i * O];
        slp_sh[half][n] = s;
    }
    __syncthreads();
    // brP[f][c][w] = beta[f][n0 + w*16 + c] * r_f   (bf16)
    #pragma unroll
    for (int j = 0; j < 32; ++j) {
        int e = t + TB * j;          // 0..8191
        int f = e >> 7;              // 0..63
        int rem = e & 127;
        int w = rem >> 4;            // 0..7
        int c = rem & 15;
        float bv = beta[f * O + n0 + w * 16 + c] * r_sh[f];
        brP_sh[f][c][w] = f_to_bf16u(bv);
    }
    __syncthreads();
    if (t < BN) {
        int c = t & 15, w = t >> 4;
        float sb = 0.f;
        #pragma unroll
        for (int f = 0; f < F; ++f) sb += bf16u_to_f(brP_sh[f][c][w]) * m_sh[f];
        c_sh[t] = bias[n0 + t] - sb * (slp_sh[0][t] + slp_sh[1][t]);
    }

    // ---- wave geometry: wave wid owns rows [m0+16*wid, +16), all 128 cols ----
    const int lane = t & 63;
    const int wid  = t >> 6;
    const int l15  = lane & 15;
    const int quad = lane >> 4;
    const int row  = m0 + wid * 16 + l15;

    floatx4 oacc[8];
    #pragma unroll
    for (int nt = 0; nt < 8; ++nt) oacc[nt] = (floatx4){0.f, 0.f, 0.f, 0.f};
    const floatx4 zero4 = (floatx4){0.f, 0.f, 0.f, 0.f};

    #pragma unroll 1
    for (int it = 0; it < 8; ++it) {
        const int i0 = it * 64;
        // lambda tile -> LDS (bf16), once per i-tile (verbatim round-3).
        // Protected by the last barrier of the previous i-tile's f-loop.
        {
            int n  = t & 127;
            int kh = t >> 7;           // 0..1
            const float* lp = lamb + (size_t)(i0 + kh * 32) * O + n0 + n;
            float v[32];
            #pragma unroll
            for (int k = 0; k < 32; ++k) v[k] = lp[(size_t)k * O];
            #pragma unroll
            for (int rr = 0; rr < 4; ++rr) {
                uintx4 w4;
                w4.x = pk_bf16(v[rr*8+0], v[rr*8+1]);
                w4.y = pk_bf16(v[rr*8+2], v[rr*8+3]);
                w4.z = pk_bf16(v[rr*8+4], v[rr*8+5]);
                w4.w = pk_bf16(v[rr*8+6], v[rr*8+7]);
                *(uintx4*)&L_sh[n][kh * 32 + rr * 8] = w4;
            }
        }
        // x -> regs: exactly the 16 values this lane's A-frags need.
        float xr0[8], xr1[8];
        {
            const float* xp = x + (size_t)row * I + i0 + quad * 8;
            float4 a0 = *(const float4*)(xp);
            float4 a1 = *(const float4*)(xp + 4);
            float4 b0 = *(const float4*)(xp + 32);
            float4 b1 = *(const float4*)(xp + 36);
            xr0[0]=a0.x; xr0[1]=a0.y; xr0[2]=a0.z; xr0[3]=a0.w;
            xr0[4]=a1.x; xr0[5]=a1.y; xr0[6]=a1.z; xr0[7]=a1.w;
            xr1[0]=b0.x; xr1[1]=b0.y; xr1[2]=b0.z; xr1[3]=b0.w;
            xr1[4]=b1.x; xr1[5]=b1.y; xr1[6]=b1.z; xr1[7]=b1.w;
        }
        // A fragments for f=0 and f=1 (registers)
        short8 afA0 = sin_frag8(xr0, wrev_sh[0], prev_sh[0]);
        short8 afA1 = sin_frag8(xr1, wrev_sh[0], prev_sh[0]);
        short8 afB0 = sin_frag8(xr0, wrev_sh[1], prev_sh[1]);
        short8 afB1 = sin_frag8(xr1, wrev_sh[1], prev_sh[1]);
        __syncthreads();   // L_sh ready
        // lambda fragments (f-invariant within this i-tile) -> registers
        short8 lf[2][8];
        #pragma unroll
        for (int kk = 0; kk < 2; ++kk)
            #pragma unroll
            for (int nt = 0; nt < 8; ++nt)
                lf[kk][nt] = *(const short8*)&L_sh[nt*16 + l15][kk*32 + quad*8];

        // betaR prefetch for f=0,1
        ushort4t bruA0 = *(const ushort4t*)&brP_sh[0][l15][0];
        ushort4t bruA1 = *(const ushort4t*)&brP_sh[0][l15][4];
        ushort4t bruB0 = *(const ushort4t*)&brP_sh[1][l15][0];
        ushort4t bruB1 = *(const ushort4t*)&brP_sh[1][l15][4];

        // ---- f-loop: 2 f per iteration, ONE barrier per pair.
        //      sin/brP for (f+2,f+3) overlap MFMA of (f,f+1). ----
        #pragma unroll 1
        for (int f = 0; f < F; f += 2) {
            float brA[8], brB[8];
            #pragma unroll
            for (int q = 0; q < 4; ++q) {
                brA[q]     = bf16u_to_f(bruA0[q]);
                brA[4 + q] = bf16u_to_f(bruA1[q]);
                brB[q]     = bf16u_to_f(bruB0[q]);
                brB[4 + q] = bf16u_to_f(bruB1[q]);
            }
            // overlap: prefetch betaR + sin fragments for f+2, f+3
            short8 nfA0 = afA0, nfA1 = afA1, nfB0 = afB0, nfB1 = afB1;
            if (f + 2 < F) {
                bruA0 = *(const ushort4t*)&brP_sh[f + 2][l15][0];
                bruA1 = *(const ushort4t*)&brP_sh[f + 2][l15][4];
                bruB0 = *(const ushort4t*)&brP_sh[f + 3][l15][0];
                bruB1 = *(const ushort4t*)&brP_sh[f + 3][l15][4];
                float wA = wrev_sh[f + 2], pA = prev_sh[f + 2];
                float wB = wrev_sh[f + 3], pB = prev_sh[f + 3];
                nfA0 = sin_frag8(xr0, wA, pA);
                nfA1 = sin_frag8(xr1, wA, pA);
                nfB0 = sin_frag8(xr0, wB, pB);
                nfB1 = sin_frag8(xr1, wB, pB);
            }
            // S_f = A_f @ Lambda ; out += betaR (.) S_f   (two independent chains)
            #pragma unroll
            for (int nt = 0; nt < 8; ++nt) {
                floatx4 s = __builtin_amdgcn_mfma_f32_16x16x32_bf16(
                    afA0, lf[0][nt], zero4, 0, 0, 0);
                s = __builtin_amdgcn_mfma_f32_16x16x32_bf16(
                    afA1, lf[1][nt], s, 0, 0, 0);
                oacc[nt] += brA[nt] * s;
            }
            #pragma unroll
            for (int nt = 0; nt < 8; ++nt) {
                floatx4 s = __builtin_amdgcn_mfma_f32_16x16x32_bf16(
                    afB0, lf[0][nt], zero4, 0, 0, 0);
                s = __builtin_amdgcn_mfma_f32_16x16x32_bf16(
                    afB1, lf[1][nt], s, 0, 0, 0);
                oacc[nt] += brB[nt] * s;
            }
            __syncthreads();
            afA0 = nfA0; afA1 = nfA1; afB0 = nfB0; afB1 = nfB1;
        }
    }

    // ---- epilogue: add per-column constant, store fp32 ----
    #pragma unroll
    for (int nt = 0; nt < 8; ++nt) {
        int gn = n0 + nt*16 + l15;
        float cv = c_sh[nt*16 + l15];
        int gm = m0 + wid*16 + quad*4;
        #pragma unroll
        for (int rg = 0; rg < 4; ++rg) {
            out[(size_t)(gm + rg) * O + gn] = oacc[nt][rg] + cv;
        }
    }
}

extern "C" void kernel_launch(void* const* d_in, const int* in_sizes, int n_in,
                              void* d_out, int out_size, void* d_ws, size_t ws_size,
                              hipStream_t stream) {
    const float* x      = (const float*)d_in[0];
    const float* freqs  = (const float*)d_in[1];
    const float* phases = (const float*)d_in[2];
    const float* beta   = (const float*)d_in[3];
    const float* lamb   = (const float*)d_in[4];
    const float* bias   = (const float*)d_in[5];
    float* out = (float*)d_out;

    dim3 grid(512);   // (8192/64) m-blocks * (512/128) n-blocks
    dim3 block(TB);
    hipLaunchKernelGGL(actlayer_kernel, grid, block, 0, stream,
                       x, freqs, phases, beta, lamb, bias, out);
}

// Round 8
// 457.781 us; speedup vs baseline: 2.2496x; 1.0502x over previous
//
#include <hip/hip_runtime.h>
#include <hip/hip_bf16.h>

// ActLayer: out[b,o] = sum_{i,f} norm(sin(w_f x[b,i] + p_f)) * beta[f,o] * lamb[i,o] + bias[o]
//
// Round-10: R7 (480us, verified) with ONE change: the fp32->bf16x2 pack.
// __float22bfloat162_rn has no cvt_pk builtin on gfx950 and expands to a
// multi-op integer-RNE sequence per value (~10 VALU ops per pair). Replaced by:
//   u += 0x8000 (round-half-up, safe: |sin|<=1, no inf/NaN production)
//   one v_perm_b32 merging the two high halves  -> 3 ops per pair.
// Applied in sin_frag8 and the lambda staging pack. Everything else is
// byte-identical to R7: pair-fused f-loop (barrier per 2 f), rintf range
// reduction, register brP prefetch, L_sh staging, epilogue.
//
// B=8192, I=512, F=64, O=512. BM=64, BN=128, i-chunk 64 (one f per K-step).
// 256 threads = 4 waves, wave w owns rows [m0+16w,+16) x 128 cols,
// mfma 16x16x32 bf16. Grid = 512 -> 2 blocks/CU.

#define TB 256

typedef __attribute__((ext_vector_type(8))) short short8;
typedef __attribute__((ext_vector_type(4))) float floatx4;
typedef __attribute__((ext_vector_type(4))) unsigned int uintx4;
typedef __attribute__((ext_vector_type(4))) unsigned short ushort4t;

// pack two fp32 -> two bf16 (round-half-up) in ONE v_perm_b32 + two v_add.
// result: low16 = bf16(a), high16 = bf16(b)  (same layout as __float22bfloat162_rn)
__device__ __forceinline__ unsigned pk_bf16(float a, float b) {
    union { float f; unsigned u; } ca, cb;
    ca.f = a; cb.f = b;
    unsigned ua = ca.u + 0x8000u;
    unsigned ub = cb.u + 0x8000u;
    // bytes: out = [ub.b3, ub.b2, ua.b3, ua.b2]
    return __builtin_amdgcn_perm(ub, ua, 0x07060302u);
}
__device__ __forceinline__ unsigned short f_to_bf16u(float v) {
    union { __hip_bfloat16 h; unsigned short u; } cv;
    cv.h = __float2bfloat16(v);
    return cv.u;
}
__device__ __forceinline__ float bf16u_to_f(unsigned short v) {
    union { unsigned u; float f; } cv; cv.u = ((unsigned)v) << 16; return cv.f;
}

// 8 bf16 sin values: sin(2*pi*(x*wfr + pfr)) for 8 register-resident x values.
// Range reduction via rndne (full-rate): u = t - round(t); sin(2*pi*u) exact.
__device__ __forceinline__ short8 sin_frag8(const float xv[8], float wfr, float pfr) {
    float s[8];
    #pragma unroll
    for (int j = 0; j < 8; ++j) {
        float t = fmaf(xv[j], wfr, pfr);
        float u = t - __builtin_rintf(t);
        s[j] = __builtin_amdgcn_sinf(u);
    }
    union { uintx4 u; short8 h; } cv;
    cv.u.x = pk_bf16(s[0], s[1]); cv.u.y = pk_bf16(s[2], s[3]);
    cv.u.z = pk_bf16(s[4], s[5]); cv.u.w = pk_bf16(s[6], s[7]);
    return cv.h;
}

__global__ __launch_bounds__(TB, 2)
void actlayer_kernel(const float* __restrict__ x,
                     const float* __restrict__ freqs,
                     const float* __restrict__ phases,
                     const float* __restrict__ beta,
                     const float* __restrict__ lamb,
                     const float* __restrict__ bias,
                     float* __restrict__ out)
{
    constexpr int I = 512, F = 64, O = 512;
    constexpr int BN = 128;
    const int t  = threadIdx.x;
    const int bx = blockIdx.x;
    const int bn = bx & 3;            // 0..3
    const int bm = bx >> 2;           // 0..127
    const int n0 = bn * BN;
    const int m0 = bm * 64;

    // pad 72 shorts = 144 B rows: 16B-aligned for b128 everywhere
    __shared__ __align__(16) unsigned short L_sh[BN][72];      // lambda tile (bf16), per i-tile
    __shared__ __align__(16) unsigned short brP_sh[F][16][12]; // betaR bf16: [f][c=o%16][w=o/16]
    __shared__ float wrev_sh[F], prev_sh[F], r_sh[F], m_sh[F];
    __shared__ float c_sh[BN];
    __shared__ float slp_sh[2][BN];

    // ---- prologue: per-f normalization constants (verbatim R7) ----
    if (t < F) {
        float wq = freqs[t];
        float ph = phases[t];
        float e1 = expf(-0.5f * wq * wq);
        float mean = e1 * sinf(ph);
        float e2 = expf(-2.0f * wq * wq);
        float var = 0.5f - 0.5f * e2 * cosf(2.0f * ph) - mean * mean;
        float r = 1.0f / sqrtf(1e-3f + var);
        wrev_sh[t] = wq * 0.15915494309189535f;   // /2pi -> revolutions for v_sin
        prev_sh[t] = ph * 0.15915494309189535f;
        r_sh[t] = r;
        m_sh[t] = mean;
    }
    // sl[n] = sum_i lamb[i][n0+n], split over 2 halves of i
    {
        int n = t & 127, half = t >> 7;
        float s = 0.f;
        const float* lp = lamb + (size_t)(half * 256) * O + n0 + n;
        #pragma unroll 8
        for (int i = 0; i < 256; ++i) s += lp[(size_t)i * O];
        slp_sh[half][n] = s;
    }
    __syncthreads();
    // brP[f][c][w] = beta[f][n0 + w*16 + c] * r_f   (bf16)
    #pragma unroll
    for (int j = 0; j < 32; ++j) {
        int e = t + TB * j;          // 0..8191
        int f = e >> 7;              // 0..63
        int rem = e & 127;
        int w = rem >> 4;            // 0..7
        int c = rem & 15;
        float bv = beta[f * O + n0 + w * 16 + c] * r_sh[f];
        brP_sh[f][c][w] = f_to_bf16u(bv);
    }
    __syncthreads();
    if (t < BN) {
        int c = t & 15, w = t >> 4;
        float sb = 0.f;
        #pragma unroll
        for (int f = 0; f < F; ++f) sb += bf16u_to_f(brP_sh[f][c][w]) * m_sh[f];
        c_sh[t] = bias[n0 + t] - sb * (slp_sh[0][t] + slp_sh[1][t]);
    }

    // ---- wave geometry: wave wid owns rows [m0+16*wid, +16), all 128 cols ----
    const int lane = t & 63;
    const int wid  = t >> 6;
    const int l15  = lane & 15;
    const int quad = lane >> 4;
    const int row  = m0 + wid * 16 + l15;

    floatx4 oacc[8];
    #pragma unroll
    for (int nt = 0; nt < 8; ++nt) oacc[nt] = (floatx4){0.f, 0.f, 0.f, 0.f};
    const floatx4 zero4 = (floatx4){0.f, 0.f, 0.f, 0.f};

    #pragma unroll 1
    for (int it = 0; it < 8; ++it) {
        const int i0 = it * 64;
        // lambda tile -> LDS (bf16), once per i-tile (verbatim R7, new pack).
        // Protected by the last barrier of the previous i-tile's f-loop.
        {
            int n  = t & 127;
            int kh = t >> 7;           // 0..1
            const float* lp = lamb + (size_t)(i0 + kh * 32) * O + n0 + n;
            float v[32];
            #pragma unroll
            for (int k = 0; k < 32; ++k) v[k] = lp[(size_t)k * O];
            #pragma unroll
            for (int rr = 0; rr < 4; ++rr) {
                uintx4 w4;
                w4.x = pk_bf16(v[rr*8+0], v[rr*8+1]);
                w4.y = pk_bf16(v[rr*8+2], v[rr*8+3]);
                w4.z = pk_bf16(v[rr*8+4], v[rr*8+5]);
                w4.w = pk_bf16(v[rr*8+6], v[rr*8+7]);
                *(uintx4*)&L_sh[n][kh * 32 + rr * 8] = w4;
            }
        }
        // x -> regs: exactly the 16 values this lane's A-frags need.
        float xr0[8], xr1[8];
        {
            const float* xp = x + (size_t)row * I + i0 + quad * 8;
            float4 a0 = *(const float4*)(xp);
            float4 a1 = *(const float4*)(xp + 4);
            float4 b0 = *(const float4*)(xp + 32);
            float4 b1 = *(const float4*)(xp + 36);
            xr0[0]=a0.x; xr0[1]=a0.y; xr0[2]=a0.z; xr0[3]=a0.w;
            xr0[4]=a1.x; xr0[5]=a1.y; xr0[6]=a1.z; xr0[7]=a1.w;
            xr1[0]=b0.x; xr1[1]=b0.y; xr1[2]=b0.z; xr1[3]=b0.w;
            xr1[4]=b1.x; xr1[5]=b1.y; xr1[6]=b1.z; xr1[7]=b1.w;
        }
        // A fragments for f=0 and f=1 (registers)
        short8 afA0 = sin_frag8(xr0, wrev_sh[0], prev_sh[0]);
        short8 afA1 = sin_frag8(xr1, wrev_sh[0], prev_sh[0]);
        short8 afB0 = sin_frag8(xr0, wrev_sh[1], prev_sh[1]);
        short8 afB1 = sin_frag8(xr1, wrev_sh[1], prev_sh[1]);
        __syncthreads();   // L_sh ready
        // lambda fragments (f-invariant within this i-tile) -> registers
        short8 lf[2][8];
        #pragma unroll
        for (int kk = 0; kk < 2; ++kk)
            #pragma unroll
            for (int nt = 0; nt < 8; ++nt)
                lf[kk][nt] = *(const short8*)&L_sh[nt*16 + l15][kk*32 + quad*8];

        // betaR prefetch for f=0,1
        ushort4t bruA0 = *(const ushort4t*)&brP_sh[0][l15][0];
        ushort4t bruA1 = *(const ushort4t*)&brP_sh[0][l15][4];
        ushort4t bruB0 = *(const ushort4t*)&brP_sh[1][l15][0];
        ushort4t bruB1 = *(const ushort4t*)&brP_sh[1][l15][4];

        // ---- f-loop: 2 f per iteration, ONE barrier per pair.
        //      sin/brP for (f+2,f+3) overlap MFMA of (f,f+1). ----
        #pragma unroll 1
        for (int f = 0; f < F; f += 2) {
            float brA[8], brB[8];
            #pragma unroll
            for (int q = 0; q < 4; ++q) {
                brA[q]     = bf16u_to_f(bruA0[q]);
                brA[4 + q] = bf16u_to_f(bruA1[q]);
                brB[q]     = bf16u_to_f(bruB0[q]);
                brB[4 + q] = bf16u_to_f(bruB1[q]);
            }
            // overlap: prefetch betaR + sin fragments for f+2, f+3
            short8 nfA0 = afA0, nfA1 = afA1, nfB0 = afB0, nfB1 = afB1;
            if (f + 2 < F) {
                bruA0 = *(const ushort4t*)&brP_sh[f + 2][l15][0];
                bruA1 = *(const ushort4t*)&brP_sh[f + 2][l15][4];
                bruB0 = *(const ushort4t*)&brP_sh[f + 3][l15][0];
                bruB1 = *(const ushort4t*)&brP_sh[f + 3][l15][4];
                float wA = wrev_sh[f + 2], pA = prev_sh[f + 2];
                float wB = wrev_sh[f + 3], pB = prev_sh[f + 3];
                nfA0 = sin_frag8(xr0, wA, pA);
                nfA1 = sin_frag8(xr1, wA, pA);
                nfB0 = sin_frag8(xr0, wB, pB);
                nfB1 = sin_frag8(xr1, wB, pB);
            }
            // S_f = A_f @ Lambda ; out += betaR (.) S_f   (two independent chains)
            #pragma unroll
            for (int nt = 0; nt < 8; ++nt) {
                floatx4 s = __builtin_amdgcn_mfma_f32_16x16x32_bf16(
                    afA0, lf[0][nt], zero4, 0, 0, 0);
                s = __builtin_amdgcn_mfma_f32_16x16x32_bf16(
                    afA1, lf[1][nt], s, 0, 0, 0);
                oacc[nt] += brA[nt] * s;
            }
            #pragma unroll
            for (int nt = 0; nt < 8; ++nt) {
                floatx4 s = __builtin_amdgcn_mfma_f32_16x16x32_bf16(
                    afB0, lf[0][nt], zero4, 0, 0, 0);
                s = __builtin_amdgcn_mfma_f32_16x16x32_bf16(
                    afB1, lf[1][nt], s, 0, 0, 0);
                oacc[nt] += brB[nt] * s;
            }
            __syncthreads();
            afA0 = nfA0; afA1 = nfA1; afB0 = nfB0; afB1 = nfB1;
        }
    }

    // ---- epilogue: add per-column constant, store fp32 ----
    #pragma unroll
    for (int nt = 0; nt < 8; ++nt) {
        int gn = n0 + nt*16 + l15;
        float cv = c_sh[nt*16 + l15];
        int gm = m0 + wid*16 + quad*4;
        #pragma unroll
        for (int rg = 0; rg < 4; ++rg) {
            out[(size_t)(gm + rg) * O + gn] = oacc[nt][rg] + cv;
        }
    }
}

extern "C" void kernel_launch(void* const* d_in, const int* in_sizes, int n_in,
                              void* d_out, int out_size, void* d_ws, size_t ws_size,
                              hipStream_t stream) {
    const float* x      = (const float*)d_in[0];
    const float* freqs  = (const float*)d_in[1];
    const float* phases = (const float*)d_in[2];
    const float* beta   = (const float*)d_in[3];
    const float* lamb   = (const float*)d_in[4];
    const float* bias   = (const float*)d_in[5];
    float* out = (float*)d_out;

    dim3 grid(512);   // (8192/64) m-blocks * (512/128) n-blocks
    dim3 block(TB);
    hipLaunchKernelGGL(actlayer_kernel, grid, block, 0, stream,
                       x, freqs, phases, beta, lamb, bias, out);
}